// Round 6
// baseline (1268.004 us; speedup 1.0000x reference)
//
#include <hip/hip_runtime.h>
#include <hip/hip_bf16.h>

// Problem constants
#define R_TOT   8192
#define A14     14
#define A_TOT   (R_TOT * A14)     // 114688
#define QR_ELEMS (R_TOT * 256)    // 2097152

typedef __attribute__((ext_vector_type(8))) short bf16x8;
typedef __attribute__((ext_vector_type(4))) float f32x4;
typedef __attribute__((ext_vector_type(4))) short short4v;

#define MFMA16(a, b, c) __builtin_amdgcn_mfma_f32_16x16x32_bf16((a), (b), (c), 0, 0, 0)

static __device__ __forceinline__ short f2b(float x) {
    __hip_bfloat16 h = __float2bfloat16(x);
    return *reinterpret_cast<short*>(&h);
}

// A-fragment of z from q (cols kc..kc+7 < 256), direct from global
static __device__ __forceinline__ bf16x8 qfrag(const float* __restrict__ q,
                                               size_t arow, int kc) {
    const float4 v0 = *(const float4*)&q[arow * 256 + kc];
    const float4 v1 = *(const float4*)&q[arow * 256 + kc + 4];
    bf16x8 r;
    r[0] = f2b(v0.x); r[1] = f2b(v0.y); r[2] = f2b(v0.z); r[3] = f2b(v0.w);
    r[4] = f2b(v1.x); r[5] = f2b(v1.y); r[6] = f2b(v1.z); r[7] = f2b(v1.w);
    return r;
}

// A-fragment of z from norm(p) (z cols 256.., cc = kc-256), on-the-fly norm
static __device__ __forceinline__ bf16x8 nfrag(const float* __restrict__ p,
                                               size_t arow, int cc) {
    const float* base = p + arow * 768 + cc;
    const float4 a0 = *(const float4*)(base);
    const float4 a1 = *(const float4*)(base + 4);
    const float4 b0 = *(const float4*)(base + 256);
    const float4 b1 = *(const float4*)(base + 260);
    const float4 c0 = *(const float4*)(base + 512);
    const float4 c1 = *(const float4*)(base + 516);
    bf16x8 r;
    r[0] = f2b(sqrtf(a0.x*a0.x + b0.x*b0.x + c0.x*c0.x + 1e-6f));
    r[1] = f2b(sqrtf(a0.y*a0.y + b0.y*b0.y + c0.y*c0.y + 1e-6f));
    r[2] = f2b(sqrtf(a0.z*a0.z + b0.z*b0.z + c0.z*c0.z + 1e-6f));
    r[3] = f2b(sqrtf(a0.w*a0.w + b0.w*b0.w + c0.w*c0.w + 1e-6f));
    r[4] = f2b(sqrtf(a1.x*a1.x + b1.x*b1.x + c1.x*c1.x + 1e-6f));
    r[5] = f2b(sqrtf(a1.y*a1.y + b1.y*b1.y + c1.y*c1.y + 1e-6f));
    r[6] = f2b(sqrtf(a1.z*a1.z + b1.z*b1.z + c1.z*c1.z + 1e-6f));
    r[7] = f2b(sqrtf(a1.w*a1.w + b1.w*b1.w + c1.w*c1.w + 1e-6f));
    return r;
}

// ---------------------------------------------------------------------------
// Weight transpose + bf16 cast:  w[K][N] fp32  ->  wT[N][K] bf16
// ---------------------------------------------------------------------------
__global__ __launch_bounds__(256) void wtrans_kernel(
    const float* __restrict__ w, __hip_bfloat16* __restrict__ wT, int K, int N)
{
    __shared__ float tile[32][33];
    const int kb = blockIdx.x * 32, nb = blockIdx.y * 32;
    const int tx = threadIdx.x & 31, ty = threadIdx.x >> 5;   // 32 x 8
    #pragma unroll
    for (int i = 0; i < 32; i += 8) {
        int k = kb + ty + i, n = nb + tx;
        tile[ty + i][tx] = (k < K && n < N) ? w[(size_t)k * N + n] : 0.f;
    }
    __syncthreads();
    #pragma unroll
    for (int i = 0; i < 32; i += 8) {
        int n = nb + ty + i, k = kb + tx;
        if (n < N && k < K) wT[(size_t)n * K + k] = __float2bfloat16(tile[tx][ty + i]);
    }
}

// ---------------------------------------------------------------------------
// Fused sam MLP + masked softmax + pooling, latency-optimized v3.
// Block = 2 residues (28 atoms, pad M=32), 256 threads = 4 waves (N-split).
// NO z staging: L1 A-fragments built directly from global q/p in registers
// (on-the-fly norm), A+B one-step register double-buffer. h1 and h2 in
// separate LDS buffers -> only 4 barriers total.
// LDS: h1 16,896 + h2 16,896 + sa 2,048 + aw 1,792 = 37,632 B -> 4 blocks/CU.
// ---------------------------------------------------------------------------
__global__ __launch_bounds__(256, 4) void sampool_kernel(
    const float* __restrict__ q, const float* __restrict__ p,
    const float* __restrict__ atom_mask,
    const __hip_bfloat16* __restrict__ wT1, const float* __restrict__ b1,
    const __hip_bfloat16* __restrict__ wT2, const float* __restrict__ b2,
    const __hip_bfloat16* __restrict__ wT3, const float* __restrict__ b3,
    __hip_bfloat16* __restrict__ qh, __hip_bfloat16* __restrict__ ph)
{
    __shared__ __align__(16) __hip_bfloat16 h1l[32][264];   // 16,896 B
    __shared__ __align__(16) __hip_bfloat16 h2l[32][264];   // 16,896 B
    __shared__ float sa_lds[32][16];                        //  2,048 B
    __shared__ float aw_lds[2][2][14][8];                   //  1,792 B

    const int tid = threadIdx.x;
    const int r0  = blockIdx.x * 2;      // 2 residues
    const int a0  = r0 * A14;            // 28 real atom rows, pad to 32
    const int wv  = tid >> 6;
    const int l   = tid & 63;
    const int lr  = l & 15;
    const int lh  = l >> 4;
    const int nbase = wv * 64;

    const int ar0 = a0 + lr;
    const int ar1 = a0 + 16 + lr;
    const size_t arow0 = (size_t)((ar0 < A_TOT) ? ar0 : (A_TOT - 1));
    const size_t arow1 = (size_t)((ar1 < A_TOT) ? ar1 : (A_TOT - 1));

    // ---- Layer 1: K=512 -> N=256 (64/wave), leaky; A direct-global + dbuf ----
    {
        f32x4 acc[2][4] = {};
        const __hip_bfloat16* pB[4];
        #pragma unroll
        for (int nt = 0; nt < 4; ++nt)
            pB[nt] = wT1 + (size_t)(nbase + nt * 16 + lr) * 512 + lh * 8;
        bf16x8 bc[4];
        #pragma unroll
        for (int nt = 0; nt < 4; ++nt) bc[nt] = *(const bf16x8*)(pB[nt]);
        bf16x8 a0c = qfrag(q, arow0, lh * 8);
        bf16x8 a1c = qfrag(q, arow1, lh * 8);

        #pragma unroll
        for (int k0 = 0; k0 < 512; k0 += 32) {
            bf16x8 bn[4], a0n, a1n;
            const int kn = k0 + 32;
            if (kn < 512) {
                #pragma unroll
                for (int nt = 0; nt < 4; ++nt)
                    bn[nt] = *(const bf16x8*)(pB[nt] + kn);
                if (kn < 256) {
                    a0n = qfrag(q, arow0, kn + lh * 8);
                    a1n = qfrag(q, arow1, kn + lh * 8);
                } else {
                    a0n = nfrag(p, arow0, kn - 256 + lh * 8);
                    a1n = nfrag(p, arow1, kn - 256 + lh * 8);
                }
            }
            #pragma unroll
            for (int nt = 0; nt < 4; ++nt) {
                acc[0][nt] = MFMA16(a0c, bc[nt], acc[0][nt]);
                acc[1][nt] = MFMA16(a1c, bc[nt], acc[1][nt]);
            }
            #pragma unroll
            for (int nt = 0; nt < 4; ++nt) bc[nt] = bn[nt];
            a0c = a0n; a1c = a1n;
        }
        #pragma unroll
        for (int nt = 0; nt < 4; ++nt) {
            const int n = nbase + nt * 16 + lr;
            const float bv = b1[n];
            #pragma unroll
            for (int mt = 0; mt < 2; ++mt)
                #pragma unroll
                for (int v = 0; v < 4; ++v) {
                    float x = acc[mt][nt][v] + bv;
                    x = x >= 0.f ? x : 0.01f * x;
                    h1l[mt * 16 + lh * 4 + v][n] = __float2bfloat16(x);
                }
        }
    }
    __syncthreads();   // (1) h1 complete

    // ---- Layer 2: K=256, leaky; A from h1l, out to h2l (separate buffer) ----
    {
        f32x4 acc[2][4] = {};
        const __hip_bfloat16* pB[4];
        #pragma unroll
        for (int nt = 0; nt < 4; ++nt)
            pB[nt] = wT2 + (size_t)(nbase + nt * 16 + lr) * 256 + lh * 8;
        bf16x8 bc[4];
        #pragma unroll
        for (int nt = 0; nt < 4; ++nt) bc[nt] = *(const bf16x8*)(pB[nt]);
        #pragma unroll
        for (int k0 = 0; k0 < 256; k0 += 32) {
            bf16x8 bn[4];
            const int kn = k0 + 32;
            if (kn < 256) {
                #pragma unroll
                for (int nt = 0; nt < 4; ++nt)
                    bn[nt] = *(const bf16x8*)(pB[nt] + kn);
            }
            const int kc = k0 + lh * 8;
            const bf16x8 a0f = *(const bf16x8*)&h1l[lr][kc];
            const bf16x8 a1f = *(const bf16x8*)&h1l[16 + lr][kc];
            #pragma unroll
            for (int nt = 0; nt < 4; ++nt) {
                acc[0][nt] = MFMA16(a0f, bc[nt], acc[0][nt]);
                acc[1][nt] = MFMA16(a1f, bc[nt], acc[1][nt]);
            }
            #pragma unroll
            for (int nt = 0; nt < 4; ++nt) bc[nt] = bn[nt];
        }
        #pragma unroll
        for (int nt = 0; nt < 4; ++nt) {
            const int n = nbase + nt * 16 + lr;
            const float bv = b2[n];
            #pragma unroll
            for (int mt = 0; mt < 2; ++mt)
                #pragma unroll
                for (int v = 0; v < 4; ++v) {
                    float x = acc[mt][nt][v] + bv;
                    x = x >= 0.f ? x : 0.01f * x;
                    h2l[mt * 16 + lh * 4 + v][n] = __float2bfloat16(x);
                }
        }
    }
    __syncthreads();   // (2) h2 complete

    // ---- Layer 3: K=256 -> 16 cols; waves 0,1 own m-frags 0,1 ----
    if (wv < 2) {
        f32x4 a3 = {};
        const __hip_bfloat16* pW3 = wT3 + (size_t)lr * 256 + lh * 8;
        bf16x8 bwc = *(const bf16x8*)(pW3);
        #pragma unroll
        for (int k0 = 0; k0 < 256; k0 += 32) {
            bf16x8 bwn;
            if (k0 + 32 < 256) bwn = *(const bf16x8*)(pW3 + k0 + 32);
            const int kc = k0 + lh * 8;
            const bf16x8 af = *(const bf16x8*)&h2l[wv * 16 + lr][kc];
            a3 = MFMA16(af, bwc, a3);
            bwc = bwn;
        }
        const float bv = b3[lr];
        #pragma unroll
        for (int v = 0; v < 4; ++v)
            sa_lds[wv * 16 + lh * 4 + v][lr] = a3[v] + bv;
    }
    __syncthreads();   // (3) sa complete

    // ---- masked softmax: 2 residues x 16 channels = 32 threads ----
    if (tid < 32) {
        const int res = tid >> 4, ch = tid & 15;
        const size_t rg = (size_t)(r0 + res);
        float sl[14];
        float mx = -3.0e38f, anym = 0.f;
        #pragma unroll
        for (int a = 0; a < 14; ++a) {
            const float m = atom_mask[rg * 14 + a];
            anym = fmaxf(anym, m);
            const float lm = (1.0f - m + 1e-6f) / (m - 1e-6f);
            const float v = sa_lds[res * 14 + a][ch] + lm;
            sl[a] = v;
            mx = fmaxf(mx, v);
        }
        float s = 0.f;
        #pragma unroll
        for (int a = 0; a < 14; ++a) { sl[a] = expf(sl[a] - mx); s += sl[a]; }
        const float inv = ((anym != 0.f) ? 1.f : 0.f) / s;   // fold residue mask
        const int h = ch >> 1;
        #pragma unroll
        for (int a = 0; a < 14; ++a)
            aw_lds[ch & 1][res][a][h] = sl[a] * inv;
    }
    __syncthreads();   // (4) aw complete

    // ---- pooling: 512 jobs = 2 res x {q,px0,px1,px2} x 64 c-quads ----
    #pragma unroll
    for (int jr = 0; jr < 2; ++jr) {
        const int job = tid + jr * 256;
        const int res = job >> 8;
        const int s   = (job >> 6) & 3;      // 0:q  1..3:p[x]
        const int c4  = (job & 63) * 4;
        const size_t rg = (size_t)(r0 + res);
        const float* const aw = &aw_lds[(s == 0) ? 0 : 1][res][0][0];
        const float* src;
        size_t stride;
        if (s == 0) { src = &q[(rg * 14) * 256 + c4]; stride = 256; }
        else        { src = &p[(rg * 14) * 768 + (size_t)(s - 1) * 256 + c4]; stride = 768; }
        float acc4[4][8] = {};
        #pragma unroll
        for (int a = 0; a < 14; ++a) {
            const float4 v = *(const float4*)(src + (size_t)a * stride);
            const float vf[4] = { v.x, v.y, v.z, v.w };
            #pragma unroll
            for (int ci = 0; ci < 4; ++ci)
                #pragma unroll
                for (int h = 0; h < 8; ++h)
                    acc4[ci][h] = fmaf(vf[ci], aw[a * 8 + h], acc4[ci][h]);
        }
        alignas(16) __hip_bfloat16 tmp[32];
        #pragma unroll
        for (int ci = 0; ci < 4; ++ci)
            #pragma unroll
            for (int h = 0; h < 8; ++h)
                tmp[ci * 8 + h] = __float2bfloat16(acc4[ci][h]);
        __hip_bfloat16* const dst = (s == 0)
            ? &qh[rg * 2048 + (size_t)c4 * 8]
            : &ph[(rg * 3 + (s - 1)) * 2048 + (size_t)c4 * 8];
        #pragma unroll
        for (int u = 0; u < 4; ++u)
            *reinterpret_cast<int4*>(dst + u * 8) = *reinterpret_cast<const int4*>(tmp + u * 8);
    }
}

// ---------------------------------------------------------------------------
// Fused zdm MLP: qh[8192][2048] -> 256 -> 256 -> 256 (qr fp32).
// ---------------------------------------------------------------------------
__global__ __launch_bounds__(256, 3) void zdm_kernel(
    const __hip_bfloat16* __restrict__ x, const __hip_bfloat16* __restrict__ zT1,
    const float* __restrict__ zb1, const __hip_bfloat16* __restrict__ zT2,
    const float* __restrict__ zb2, const __hip_bfloat16* __restrict__ zT3,
    const float* __restrict__ zb3, float* __restrict__ qr)
{
    __shared__ __align__(16) __hip_bfloat16 xl[2][32][264];  // 33,792 B
    __shared__ __align__(16) __hip_bfloat16 hl[32][264];     // 16,896 B

    const int tid = threadIdx.x;
    const int a0  = blockIdx.x * 32;
    const int wv  = tid >> 6;
    const int l   = tid & 63;
    const int lr  = l & 15;
    const int lh  = l >> 4;
    const int nbase = wv * 64;

    int4 st[4];
    #define LOADC(c)                                                          \
        { _Pragma("unroll")                                                   \
          for (int it = 0; it < 4; ++it) {                                    \
              const int g = tid + it * 256;                                   \
              const int m = g >> 5, c8 = (g & 31) * 8;                        \
              st[it] = *(const int4*)&x[(size_t)(a0 + m) * 2048 + (c) * 256 + c8]; } }
    #define WRITEC(buf)                                                       \
        { _Pragma("unroll")                                                   \
          for (int it = 0; it < 4; ++it) {                                    \
              const int g = tid + it * 256;                                   \
              const int m = g >> 5, c8 = (g & 31) * 8;                        \
              *(int4*)&xl[buf][m][c8] = st[it]; } }

    // ---- Layer 1: K=2048 ----
    f32x4 acc[2][4] = {};
    {
        const __hip_bfloat16* pB[4];
        #pragma unroll
        for (int nt = 0; nt < 4; ++nt)
            pB[nt] = zT1 + (size_t)(nbase + nt * 16 + lr) * 2048 + lh * 8;

        LOADC(0); WRITEC(0); __syncthreads();
        for (int c = 0; c < 8; ++c) {
            if (c < 7) LOADC(c + 1);            // issue next chunk early
            const __hip_bfloat16 (* const cur)[264] = xl[c & 1];
            bf16x8 bc[4];
            #pragma unroll
            for (int nt = 0; nt < 4; ++nt) bc[nt] = *(const bf16x8*)(pB[nt] + c * 256);
            #pragma unroll
            for (int k0 = 0; k0 < 256; k0 += 32) {
                bf16x8 bn[4];
                if (k0 + 32 < 256) {
                    #pragma unroll
                    for (int nt = 0; nt < 4; ++nt)
                        bn[nt] = *(const bf16x8*)(pB[nt] + c * 256 + k0 + 32);
                }
                const int kc = k0 + lh * 8;
                const bf16x8 a0f = *(const bf16x8*)&cur[lr][kc];
                const bf16x8 a1f = *(const bf16x8*)&cur[16 + lr][kc];
                #pragma unroll
                for (int nt = 0; nt < 4; ++nt) {
                    acc[0][nt] = MFMA16(a0f, bc[nt], acc[0][nt]);
                    acc[1][nt] = MFMA16(a1f, bc[nt], acc[1][nt]);
                }
                #pragma unroll
                for (int nt = 0; nt < 4; ++nt) bc[nt] = bn[nt];
            }
            if (c < 7) WRITEC((c + 1) & 1);
            __syncthreads();
        }
        #pragma unroll
        for (int nt = 0; nt < 4; ++nt) {
            const int n = nbase + nt * 16 + lr;
            const float bv = zb1[n];
            #pragma unroll
            for (int mt = 0; mt < 2; ++mt)
                #pragma unroll
                for (int v = 0; v < 4; ++v) {
                    float xv = acc[mt][nt][v] + bv;
                    xv = xv >= 0.f ? xv : 0.01f * xv;
                    hl[mt * 16 + lh * 4 + v][n] = __float2bfloat16(xv);
                }
        }
    }
    __syncthreads();

    // ---- Layer 2: K=256, leaky, write back into hl ----
    {
        f32x4 acc2[2][4] = {};
        const __hip_bfloat16* pB[4];
        #pragma unroll
        for (int nt = 0; nt < 4; ++nt)
            pB[nt] = zT2 + (size_t)(nbase + nt * 16 + lr) * 256 + lh * 8;
        bf16x8 bc[4];
        #pragma unroll
        for (int nt = 0; nt < 4; ++nt) bc[nt] = *(const bf16x8*)(pB[nt]);
        #pragma unroll
        for (int k0 = 0; k0 < 256; k0 += 32) {
            bf16x8 bn[4];
            if (k0 + 32 < 256) {
                #pragma unroll
                for (int nt = 0; nt < 4; ++nt)
                    bn[nt] = *(const bf16x8*)(pB[nt] + k0 + 32);
            }
            const int kc = k0 + lh * 8;
            const bf16x8 a0f = *(const bf16x8*)&hl[lr][kc];
            const bf16x8 a1f = *(const bf16x8*)&hl[16 + lr][kc];
            #pragma unroll
            for (int nt = 0; nt < 4; ++nt) {
                acc2[0][nt] = MFMA16(a0f, bc[nt], acc2[0][nt]);
                acc2[1][nt] = MFMA16(a1f, bc[nt], acc2[1][nt]);
            }
            #pragma unroll
            for (int nt = 0; nt < 4; ++nt) bc[nt] = bn[nt];
        }
        __syncthreads();
        #pragma unroll
        for (int nt = 0; nt < 4; ++nt) {
            const int n = nbase + nt * 16 + lr;
            const float bv = zb2[n];
            #pragma unroll
            for (int mt = 0; mt < 2; ++mt)
                #pragma unroll
                for (int v = 0; v < 4; ++v) {
                    float xv = acc2[mt][nt][v] + bv;
                    xv = xv >= 0.f ? xv : 0.01f * xv;
                    hl[mt * 16 + lh * 4 + v][n] = __float2bfloat16(xv);
                }
        }
    }
    __syncthreads();

    // ---- Layer 3: K=256 -> qr (fp32, bias, no act) ----
    {
        f32x4 acc3[2][4] = {};
        const __hip_bfloat16* pB[4];
        #pragma unroll
        for (int nt = 0; nt < 4; ++nt)
            pB[nt] = zT3 + (size_t)(nbase + nt * 16 + lr) * 256 + lh * 8;
        bf16x8 bc[4];
        #pragma unroll
        for (int nt = 0; nt < 4; ++nt) bc[nt] = *(const bf16x8*)(pB[nt]);
        #pragma unroll
        for (int k0 = 0; k0 < 256; k0 += 32) {
            bf16x8 bn[4];
            if (k0 + 32 < 256) {
                #pragma unroll
                for (int nt = 0; nt < 4; ++nt)
                    bn[nt] = *(const bf16x8*)(pB[nt] + k0 + 32);
            }
            const int kc = k0 + lh * 8;
            const bf16x8 a0f = *(const bf16x8*)&hl[lr][kc];
            const bf16x8 a1f = *(const bf16x8*)&hl[16 + lr][kc];
            #pragma unroll
            for (int nt = 0; nt < 4; ++nt) {
                acc3[0][nt] = MFMA16(a0f, bc[nt], acc3[0][nt]);
                acc3[1][nt] = MFMA16(a1f, bc[nt], acc3[1][nt]);
            }
            #pragma unroll
            for (int nt = 0; nt < 4; ++nt) bc[nt] = bn[nt];
        }
        #pragma unroll
        for (int nt = 0; nt < 4; ++nt) {
            const int n = nbase + nt * 16 + lr;
            const float bv = zb3[n];
            #pragma unroll
            for (int mt = 0; mt < 2; ++mt)
                #pragma unroll
                for (int v = 0; v < 4; ++v)
                    qr[(size_t)(a0 + mt * 16 + lh * 4 + v) * 256 + n] = acc3[mt][nt][v] + bv;
        }
    }
    #undef LOADC
    #undef WRITEC
}

// ---------------------------------------------------------------------------
// pr = ph[24576][2048] @ vT  (fp32 out, no bias/act).
// ---------------------------------------------------------------------------
__global__ __launch_bounds__(256, 3) void pr_kernel(
    const __hip_bfloat16* __restrict__ x, const __hip_bfloat16* __restrict__ vT,
    float* __restrict__ out)
{
    __shared__ __align__(16) __hip_bfloat16 xl[2][32][264];  // 33,792 B

    const int tid = threadIdx.x;
    const int a0  = blockIdx.x * 32;
    const int wv  = tid >> 6;
    const int l   = tid & 63;
    const int lr  = l & 15;
    const int lh  = l >> 4;
    const int nbase = wv * 64;

    int4 st[4];
    #define LOADC(c)                                                          \
        { _Pragma("unroll")                                                   \
          for (int it = 0; it < 4; ++it) {                                    \
              const int g = tid + it * 256;                                   \
              const int m = g >> 5, c8 = (g & 31) * 8;                        \
              st[it] = *(const int4*)&x[(size_t)(a0 + m) * 2048 + (c) * 256 + c8]; } }
    #define WRITEC(buf)                                                       \
        { _Pragma("unroll")                                                   \
          for (int it = 0; it < 4; ++it) {                                    \
              const int g = tid + it * 256;                                   \
              const int m = g >> 5, c8 = (g & 31) * 8;                        \
              *(int4*)&xl[buf][m][c8] = st[it]; } }

    f32x4 acc[2][4] = {};
    const __hip_bfloat16* pB[4];
    #pragma unroll
    for (int nt = 0; nt < 4; ++nt)
        pB[nt] = vT + (size_t)(nbase + nt * 16 + lr) * 2048 + lh * 8;

    LOADC(0); WRITEC(0); __syncthreads();
    for (int c = 0; c < 8; ++c) {
        if (c < 7) LOADC(c + 1);
        const __hip_bfloat16 (* const cur)[264] = xl[c & 1];
        bf16x8 bc[4];
        #pragma unroll
        for (int nt = 0; nt < 4; ++nt) bc[nt] = *(const bf16x8*)(pB[nt] + c * 256);
        #pragma unroll
        for (int k0 = 0; k0 < 256; k0 += 32) {
            bf16x8 bn[4];
            if (k0 + 32 < 256) {
                #pragma unroll
                for (int nt = 0; nt < 4; ++nt)
                    bn[nt] = *(const bf16x8*)(pB[nt] + c * 256 + k0 + 32);
            }
            const int kc = k0 + lh * 8;
            const bf16x8 a0f = *(const bf16x8*)&cur[lr][kc];
            const bf16x8 a1f = *(const bf16x8*)&cur[16 + lr][kc];
            #pragma unroll
            for (int nt = 0; nt < 4; ++nt) {
                acc[0][nt] = MFMA16(a0f, bc[nt], acc[0][nt]);
                acc[1][nt] = MFMA16(a1f, bc[nt], acc[1][nt]);
            }
            #pragma unroll
            for (int nt = 0; nt < 4; ++nt) bc[nt] = bn[nt];
        }
        if (c < 7) WRITEC((c + 1) & 1);
        __syncthreads();
    }
    #pragma unroll
    for (int nt = 0; nt < 4; ++nt) {
        const int n = nbase + nt * 16 + lr;
        #pragma unroll
        for (int mt = 0; mt < 2; ++mt)
            #pragma unroll
            for (int v = 0; v < 4; ++v)
                out[(size_t)(a0 + mt * 16 + lh * 4 + v) * 256 + n] = acc[mt][nt][v];
    }
    #undef LOADC
    #undef WRITEC
}

// ---------------------------------------------------------------------------
extern "C" void kernel_launch(void* const* d_in, const int* in_sizes, int n_in,
                              void* d_out, int out_size, void* d_ws, size_t ws_size,
                              hipStream_t stream)
{
    const float* q    = (const float*)d_in[0];
    const float* p    = (const float*)d_in[1];
    const float* amsk = (const float*)d_in[2];
    const float* sw1  = (const float*)d_in[3];
    const float* sb1  = (const float*)d_in[4];
    const float* sw2  = (const float*)d_in[5];
    const float* sb2  = (const float*)d_in[6];
    const float* sw3  = (const float*)d_in[7];
    const float* sb3  = (const float*)d_in[8];
    const float* zw1  = (const float*)d_in[9];
    const float* zb1  = (const float*)d_in[10];
    const float* zw2  = (const float*)d_in[11];
    const float* zb2  = (const float*)d_in[12];
    const float* zw3  = (const float*)d_in[13];
    const float* zb3  = (const float*)d_in[14];
    const float* zvw  = (const float*)d_in[15];

    // workspace carve-up
    char* ws = (char*)d_ws;
    size_t off = 0;
    __hip_bfloat16* qh   = (__hip_bfloat16*)(ws + off);  off += (size_t)R_TOT * 2048 * 2;      // 33,554,432
    __hip_bfloat16* ph   = (__hip_bfloat16*)(ws + off);  off += (size_t)R_TOT * 3 * 2048 * 2;  // 100,663,296
    __hip_bfloat16* wT1  = (__hip_bfloat16*)(ws + off);  off += 256 * 512 * 2;
    __hip_bfloat16* wT2  = (__hip_bfloat16*)(ws + off);  off += 256 * 256 * 2;
    __hip_bfloat16* wT3  = (__hip_bfloat16*)(ws + off);  off += 16 * 256 * 2;
    __hip_bfloat16* zT1  = (__hip_bfloat16*)(ws + off);  off += 256 * 2048 * 2;
    __hip_bfloat16* zT2  = (__hip_bfloat16*)(ws + off);  off += 256 * 256 * 2;
    __hip_bfloat16* zT3  = (__hip_bfloat16*)(ws + off);  off += 256 * 256 * 2;
    __hip_bfloat16* vT   = (__hip_bfloat16*)(ws + off);  off += 256 * 2048 * 2;

    float* qr = (float*)d_out;
    float* pr = (float*)d_out + QR_ELEMS;

    // 0) weight transpose + bf16 cast
    wtrans_kernel<<<dim3(16, 8), 256, 0, stream>>>(sw1, wT1, 512, 256);
    wtrans_kernel<<<dim3(8, 8),  256, 0, stream>>>(sw2, wT2, 256, 256);
    wtrans_kernel<<<dim3(8, 1),  256, 0, stream>>>(sw3, wT3, 256, 16);
    wtrans_kernel<<<dim3(64, 8), 256, 0, stream>>>(zw1, zT1, 2048, 256);
    wtrans_kernel<<<dim3(8, 8),  256, 0, stream>>>(zw2, zT2, 256, 256);
    wtrans_kernel<<<dim3(8, 8),  256, 0, stream>>>(zw3, zT3, 256, 256);
    wtrans_kernel<<<dim3(64, 8), 256, 0, stream>>>(zvw, vT, 2048, 256);

    // 1) fused sam MLP + softmax + pooling  (2 residues / block)
    sampool_kernel<<<R_TOT / 2, 256, 0, stream>>>(q, p, amsk, wT1, sb1, wT2, sb2, wT3, sb3, qh, ph);
    // 2) fused zdm MLP -> qr
    zdm_kernel<<<R_TOT / 32, 256, 0, stream>>>(qh, zT1, zb1, zT2, zb2, zT3, zb3, qr);
    // 3) pr = ph @ zdm_vec_w
    pr_kernel<<<(R_TOT * 3) / 32, 256, 0, stream>>>(ph, vT, pr);

    (void)in_sizes; (void)n_in; (void)out_size; (void)ws_size;
}

// Round 7
// 496.643 us; speedup vs baseline: 2.5532x; 2.5532x over previous
//
#include <hip/hip_runtime.h>
#include <hip/hip_bf16.h>

// Problem constants
#define R_TOT   8192
#define A14     14
#define A_TOT   (R_TOT * A14)     // 114688
#define QR_ELEMS (R_TOT * 256)    // 2097152

typedef __attribute__((ext_vector_type(8))) short bf16x8;
typedef __attribute__((ext_vector_type(4))) float f32x4;
typedef __attribute__((ext_vector_type(4))) short short4v;

#define MFMA16(a, b, c) __builtin_amdgcn_mfma_f32_16x16x32_bf16((a), (b), (c), 0, 0, 0)

static __device__ __forceinline__ float b2f(short s) {
    return __uint_as_float(((unsigned)(unsigned short)s) << 16);
}

// ---------------------------------------------------------------------------
// Weight transpose + bf16 cast:  w[K][N] fp32  ->  wT[N][K] bf16
// ---------------------------------------------------------------------------
__global__ __launch_bounds__(256) void wtrans_kernel(
    const float* __restrict__ w, __hip_bfloat16* __restrict__ wT, int K, int N)
{
    __shared__ float tile[32][33];
    const int kb = blockIdx.x * 32, nb = blockIdx.y * 32;
    const int tx = threadIdx.x & 31, ty = threadIdx.x >> 5;   // 32 x 8
    #pragma unroll
    for (int i = 0; i < 32; i += 8) {
        int k = kb + ty + i, n = nb + tx;
        tile[ty + i][tx] = (k < K && n < N) ? w[(size_t)k * N + n] : 0.f;
    }
    __syncthreads();
    #pragma unroll
    for (int i = 0; i < 32; i += 8) {
        int n = nb + ty + i, k = kb + tx;
        if (n < N && k < K) wT[(size_t)n * K + k] = __float2bfloat16(tile[tx][ty + i]);
    }
}

// ---------------------------------------------------------------------------
// Fused sam MLP + masked softmax + pooling, v4 (round-5 structure, M=64).
// Block = 4 residues = 56 atoms (pad M=64), 256 threads = 4 waves (N-split).
// z[64][520] staged bf16 once (q cols 0-255 kept live for pool; norm half
// cols 256-511 becomes h1/h2 in place after L1).  Per k-step per wave:
// 16 MFMA on 4 B-frags (2x the MFMA/B-byte of M=32), B prefetch depth 2,
// A prefetch depth 1.  LDS: 66,560 + 4,096 + 3,584 = 74,240 B -> 2 blocks/CU.
// ---------------------------------------------------------------------------
__global__ __launch_bounds__(256, 2) void sampool_kernel(
    const float* __restrict__ q, const float* __restrict__ p,
    const float* __restrict__ atom_mask,
    const __hip_bfloat16* __restrict__ wT1, const float* __restrict__ b1,
    const __hip_bfloat16* __restrict__ wT2, const float* __restrict__ b2,
    const __hip_bfloat16* __restrict__ wT3, const float* __restrict__ b3,
    __hip_bfloat16* __restrict__ qh, __hip_bfloat16* __restrict__ ph)
{
    __shared__ __align__(16) __hip_bfloat16 zl[64][520];    // 66,560 B
    __shared__ float sa_lds[64][16];                        //  4,096 B
    __shared__ float aw_lds[2][4][14][8];                   //  3,584 B

    const int tid = threadIdx.x;
    const int r0  = blockIdx.x * 4;      // 4 residues
    const int a0  = r0 * A14;            // 56 real atom rows, pad to 64
    const int wv  = tid >> 6;
    const int l   = tid & 63;
    const int lr  = l & 15;
    const int lh  = l >> 4;
    const int nbase = wv * 64;

    // ---- stage z[64][512] as bf16: q cols 0-255, ||p|| cols 256-511 ----
    #pragma unroll 4
    for (int it = 0; it < 32; ++it) {
        const int g  = tid + it * 256;       // 0..8191
        const int m  = g >> 7;               // 0..63
        const int c4 = (g & 127) * 4;        // 0..508
        const int ar = a0 + m;
        const size_t arow = (size_t)((ar < A_TOT) ? ar : (A_TOT - 1));
        __hip_bfloat16 t[4];
        if (c4 < 256) {
            const float4 v = *(const float4*)&q[arow * 256 + c4];
            t[0] = __float2bfloat16(v.x); t[1] = __float2bfloat16(v.y);
            t[2] = __float2bfloat16(v.z); t[3] = __float2bfloat16(v.w);
        } else {
            const int cc = c4 - 256;
            const float4 pa = *(const float4*)&p[arow * 768 + 0 * 256 + cc];
            const float4 pb = *(const float4*)&p[arow * 768 + 1 * 256 + cc];
            const float4 pc = *(const float4*)&p[arow * 768 + 2 * 256 + cc];
            t[0] = __float2bfloat16(sqrtf(pa.x*pa.x + pb.x*pb.x + pc.x*pc.x + 1e-6f));
            t[1] = __float2bfloat16(sqrtf(pa.y*pa.y + pb.y*pb.y + pc.y*pc.y + 1e-6f));
            t[2] = __float2bfloat16(sqrtf(pa.z*pa.z + pb.z*pb.z + pc.z*pc.z + 1e-6f));
            t[3] = __float2bfloat16(sqrtf(pa.w*pa.w + pb.w*pb.w + pc.w*pc.w + 1e-6f));
        }
        *(short4v*)&zl[m][c4] = *(const short4v*)t;
    }
    __syncthreads();   // (1) z staged

    // ---- Layer 1: K=512 -> N=256 (64/wave); 16 MFMA/k-step, B depth-2 ----
    {
        f32x4 acc[4][4] = {};
        const __hip_bfloat16* pB[4];
        #pragma unroll
        for (int nt = 0; nt < 4; ++nt)
            pB[nt] = wT1 + (size_t)(nbase + nt * 16 + lr) * 512 + lh * 8;
        bf16x8 bc[4], b1v[4];
        #pragma unroll
        for (int nt = 0; nt < 4; ++nt) { bc[nt]  = *(const bf16x8*)(pB[nt]);
                                         b1v[nt] = *(const bf16x8*)(pB[nt] + 32); }
        bf16x8 ac[4];
        #pragma unroll
        for (int mf = 0; mf < 4; ++mf)
            ac[mf] = *(const bf16x8*)&zl[mf * 16 + lr][lh * 8];

        #pragma unroll
        for (int k0 = 0; k0 < 512; k0 += 32) {
            bf16x8 b2v[4], an[4];
            if (k0 + 64 < 512) {
                #pragma unroll
                for (int nt = 0; nt < 4; ++nt)
                    b2v[nt] = *(const bf16x8*)(pB[nt] + k0 + 64);
            }
            if (k0 + 32 < 512) {
                #pragma unroll
                for (int mf = 0; mf < 4; ++mf)
                    an[mf] = *(const bf16x8*)&zl[mf * 16 + lr][k0 + 32 + lh * 8];
            }
            #pragma unroll
            for (int mf = 0; mf < 4; ++mf)
                #pragma unroll
                for (int nt = 0; nt < 4; ++nt)
                    acc[mf][nt] = MFMA16(ac[mf], bc[nt], acc[mf][nt]);
            #pragma unroll
            for (int nt = 0; nt < 4; ++nt) { bc[nt] = b1v[nt]; b1v[nt] = b2v[nt]; }
            #pragma unroll
            for (int mf = 0; mf < 4; ++mf) ac[mf] = an[mf];
        }
        __syncthreads();   // (2) all waves done reading z norm half
        #pragma unroll
        for (int nt = 0; nt < 4; ++nt) {
            const int n = nbase + nt * 16 + lr;
            const float bv = b1[n];
            #pragma unroll
            for (int mf = 0; mf < 4; ++mf)
                #pragma unroll
                for (int v = 0; v < 4; ++v) {
                    float x = acc[mf][nt][v] + bv;
                    x = x >= 0.f ? x : 0.01f * x;
                    zl[mf * 16 + lh * 4 + v][256 + n] = __float2bfloat16(x);  // h1
                }
        }
    }
    __syncthreads();   // (3) h1 complete

    // ---- Layer 2: K=256, leaky; A=h1 (z cols 256+), in-place h2 ----
    {
        f32x4 acc[4][4] = {};
        const __hip_bfloat16* pB[4];
        #pragma unroll
        for (int nt = 0; nt < 4; ++nt)
            pB[nt] = wT2 + (size_t)(nbase + nt * 16 + lr) * 256 + lh * 8;
        bf16x8 bc[4], b1v[4];
        #pragma unroll
        for (int nt = 0; nt < 4; ++nt) { bc[nt]  = *(const bf16x8*)(pB[nt]);
                                         b1v[nt] = *(const bf16x8*)(pB[nt] + 32); }
        bf16x8 ac[4];
        #pragma unroll
        for (int mf = 0; mf < 4; ++mf)
            ac[mf] = *(const bf16x8*)&zl[mf * 16 + lr][256 + lh * 8];

        #pragma unroll
        for (int k0 = 0; k0 < 256; k0 += 32) {
            bf16x8 b2v[4], an[4];
            if (k0 + 64 < 256) {
                #pragma unroll
                for (int nt = 0; nt < 4; ++nt)
                    b2v[nt] = *(const bf16x8*)(pB[nt] + k0 + 64);
            }
            if (k0 + 32 < 256) {
                #pragma unroll
                for (int mf = 0; mf < 4; ++mf)
                    an[mf] = *(const bf16x8*)&zl[mf * 16 + lr][256 + k0 + 32 + lh * 8];
            }
            #pragma unroll
            for (int mf = 0; mf < 4; ++mf)
                #pragma unroll
                for (int nt = 0; nt < 4; ++nt)
                    acc[mf][nt] = MFMA16(ac[mf], bc[nt], acc[mf][nt]);
            #pragma unroll
            for (int nt = 0; nt < 4; ++nt) { bc[nt] = b1v[nt]; b1v[nt] = b2v[nt]; }
            #pragma unroll
            for (int mf = 0; mf < 4; ++mf) ac[mf] = an[mf];
        }
        __syncthreads();   // (4) all reads of h1 done
        #pragma unroll
        for (int nt = 0; nt < 4; ++nt) {
            const int n = nbase + nt * 16 + lr;
            const float bv = b2[n];
            #pragma unroll
            for (int mf = 0; mf < 4; ++mf)
                #pragma unroll
                for (int v = 0; v < 4; ++v) {
                    float x = acc[mf][nt][v] + bv;
                    x = x >= 0.f ? x : 0.01f * x;
                    zl[mf * 16 + lh * 4 + v][256 + n] = __float2bfloat16(x);  // h2
                }
        }
    }
    __syncthreads();   // (5) h2 complete

    // ---- Layer 3: K=256 -> 16 cols; wave wv owns m-frag wv ----
    {
        f32x4 a3 = {};
        const __hip_bfloat16* pW3 = wT3 + (size_t)lr * 256 + lh * 8;
        bf16x8 bwc = *(const bf16x8*)(pW3);
        bf16x8 bw1 = *(const bf16x8*)(pW3 + 32);
        #pragma unroll
        for (int k0 = 0; k0 < 256; k0 += 32) {
            bf16x8 bw2;
            if (k0 + 64 < 256) bw2 = *(const bf16x8*)(pW3 + k0 + 64);
            const bf16x8 af = *(const bf16x8*)&zl[wv * 16 + lr][256 + k0 + lh * 8];
            a3 = MFMA16(af, bwc, a3);
            bwc = bw1; bw1 = bw2;
        }
        const float bv = b3[lr];
        #pragma unroll
        for (int v = 0; v < 4; ++v)
            sa_lds[wv * 16 + lh * 4 + v][lr] = a3[v] + bv;
    }
    __syncthreads();   // (6) sa complete

    // ---- masked softmax: 4 residues x 16 channels = 64 threads ----
    if (tid < 64) {
        const int res = tid >> 4, ch = tid & 15;
        const size_t rg = (size_t)(r0 + res);
        float sl[14];
        float mx = -3.0e38f, anym = 0.f;
        #pragma unroll
        for (int a = 0; a < 14; ++a) {
            const float m = atom_mask[rg * 14 + a];
            anym = fmaxf(anym, m);
            const float lm = (1.0f - m + 1e-6f) / (m - 1e-6f);
            const float v = sa_lds[res * 14 + a][ch] + lm;
            sl[a] = v;
            mx = fmaxf(mx, v);
        }
        float s = 0.f;
        #pragma unroll
        for (int a = 0; a < 14; ++a) { sl[a] = expf(sl[a] - mx); s += sl[a]; }
        const float inv = ((anym != 0.f) ? 1.f : 0.f) / s;   // fold residue mask
        const int h = ch >> 1;
        #pragma unroll
        for (int a = 0; a < 14; ++a)
            aw_lds[ch & 1][res][a][h] = sl[a] * inv;
    }
    __syncthreads();   // (7) aw complete

    // ---- pooling: 1024 jobs = 4 res x {q,px0,px1,px2} x 64 c-quads ----
    // q comes from LDS z (bf16, cols 0-255 still live); p from global.
    #pragma unroll
    for (int jr = 0; jr < 4; ++jr) {
        const int job = tid + jr * 256;
        const int res = job >> 8;            // 0..3
        const int s   = (job >> 6) & 3;      // 0:q  1..3:p[x]
        const int c4  = (job & 63) * 4;
        const size_t rg = (size_t)(r0 + res);
        const float* const aw = &aw_lds[(s == 0) ? 0 : 1][res][0][0];
        float acc4[4][8] = {};
        if (s == 0) {
            #pragma unroll
            for (int a = 0; a < 14; ++a) {
                const short4v qv = *(const short4v*)&zl[res * 14 + a][c4];
                const float qf[4] = { b2f(qv.x), b2f(qv.y), b2f(qv.z), b2f(qv.w) };
                #pragma unroll
                for (int ci = 0; ci < 4; ++ci)
                    #pragma unroll
                    for (int h = 0; h < 8; ++h)
                        acc4[ci][h] = fmaf(qf[ci], aw[a * 8 + h], acc4[ci][h]);
            }
        } else {
            const int x = s - 1;
            #pragma unroll
            for (int a = 0; a < 14; ++a) {
                const float4 pv = *(const float4*)&p[(rg * 14 + a) * 768 + (size_t)x * 256 + c4];
                const float pf[4] = { pv.x, pv.y, pv.z, pv.w };
                #pragma unroll
                for (int ci = 0; ci < 4; ++ci)
                    #pragma unroll
                    for (int h = 0; h < 8; ++h)
                        acc4[ci][h] = fmaf(pf[ci], aw[a * 8 + h], acc4[ci][h]);
            }
        }
        alignas(16) __hip_bfloat16 tmp[32];
        #pragma unroll
        for (int ci = 0; ci < 4; ++ci)
            #pragma unroll
            for (int h = 0; h < 8; ++h)
                tmp[ci * 8 + h] = __float2bfloat16(acc4[ci][h]);
        __hip_bfloat16* const dst = (s == 0)
            ? &qh[rg * 2048 + (size_t)c4 * 8]
            : &ph[(rg * 3 + (s - 1)) * 2048 + (size_t)c4 * 8];
        #pragma unroll
        for (int u = 0; u < 4; ++u)
            *reinterpret_cast<int4*>(dst + u * 8) = *reinterpret_cast<const int4*>(tmp + u * 8);
    }
}

// ---------------------------------------------------------------------------
// Fused zdm MLP: qh[8192][2048] -> 256 -> 256 -> 256 (qr fp32).
// ---------------------------------------------------------------------------
__global__ __launch_bounds__(256, 3) void zdm_kernel(
    const __hip_bfloat16* __restrict__ x, const __hip_bfloat16* __restrict__ zT1,
    const float* __restrict__ zb1, const __hip_bfloat16* __restrict__ zT2,
    const float* __restrict__ zb2, const __hip_bfloat16* __restrict__ zT3,
    const float* __restrict__ zb3, float* __restrict__ qr)
{
    __shared__ __align__(16) __hip_bfloat16 xl[2][32][264];  // 33,792 B
    __shared__ __align__(16) __hip_bfloat16 hl[32][264];     // 16,896 B

    const int tid = threadIdx.x;
    const int a0  = blockIdx.x * 32;
    const int wv  = tid >> 6;
    const int l   = tid & 63;
    const int lr  = l & 15;
    const int lh  = l >> 4;
    const int nbase = wv * 64;

    int4 st[4];
    #define LOADC(c)                                                          \
        { _Pragma("unroll")                                                   \
          for (int it = 0; it < 4; ++it) {                                    \
              const int g = tid + it * 256;                                   \
              const int m = g >> 5, c8 = (g & 31) * 8;                        \
              st[it] = *(const int4*)&x[(size_t)(a0 + m) * 2048 + (c) * 256 + c8]; } }
    #define WRITEC(buf)                                                       \
        { _Pragma("unroll")                                                   \
          for (int it = 0; it < 4; ++it) {                                    \
              const int g = tid + it * 256;                                   \
              const int m = g >> 5, c8 = (g & 31) * 8;                        \
              *(int4*)&xl[buf][m][c8] = st[it]; } }

    // ---- Layer 1: K=2048 ----
    f32x4 acc[2][4] = {};
    {
        const __hip_bfloat16* pB[4];
        #pragma unroll
        for (int nt = 0; nt < 4; ++nt)
            pB[nt] = zT1 + (size_t)(nbase + nt * 16 + lr) * 2048 + lh * 8;

        LOADC(0); WRITEC(0); __syncthreads();
        for (int c = 0; c < 8; ++c) {
            if (c < 7) LOADC(c + 1);            // issue next chunk early
            const __hip_bfloat16 (* const cur)[264] = xl[c & 1];
            bf16x8 bc[4];
            #pragma unroll
            for (int nt = 0; nt < 4; ++nt) bc[nt] = *(const bf16x8*)(pB[nt] + c * 256);
            #pragma unroll
            for (int k0 = 0; k0 < 256; k0 += 32) {
                bf16x8 bn[4];
                if (k0 + 32 < 256) {
                    #pragma unroll
                    for (int nt = 0; nt < 4; ++nt)
                        bn[nt] = *(const bf16x8*)(pB[nt] + c * 256 + k0 + 32);
                }
                const int kc = k0 + lh * 8;
                const bf16x8 a0f = *(const bf16x8*)&cur[lr][kc];
                const bf16x8 a1f = *(const bf16x8*)&cur[16 + lr][kc];
                #pragma unroll
                for (int nt = 0; nt < 4; ++nt) {
                    acc[0][nt] = MFMA16(a0f, bc[nt], acc[0][nt]);
                    acc[1][nt] = MFMA16(a1f, bc[nt], acc[1][nt]);
                }
                #pragma unroll
                for (int nt = 0; nt < 4; ++nt) bc[nt] = bn[nt];
            }
            if (c < 7) WRITEC((c + 1) & 1);
            __syncthreads();
        }
        #pragma unroll
        for (int nt = 0; nt < 4; ++nt) {
            const int n = nbase + nt * 16 + lr;
            const float bv = zb1[n];
            #pragma unroll
            for (int mt = 0; mt < 2; ++mt)
                #pragma unroll
                for (int v = 0; v < 4; ++v) {
                    float xv = acc[mt][nt][v] + bv;
                    xv = xv >= 0.f ? xv : 0.01f * xv;
                    hl[mt * 16 + lh * 4 + v][n] = __float2bfloat16(xv);
                }
        }
    }
    __syncthreads();

    // ---- Layer 2: K=256, leaky, write back into hl ----
    {
        f32x4 acc2[2][4] = {};
        const __hip_bfloat16* pB[4];
        #pragma unroll
        for (int nt = 0; nt < 4; ++nt)
            pB[nt] = zT2 + (size_t)(nbase + nt * 16 + lr) * 256 + lh * 8;
        bf16x8 bc[4];
        #pragma unroll
        for (int nt = 0; nt < 4; ++nt) bc[nt] = *(const bf16x8*)(pB[nt]);
        #pragma unroll
        for (int k0 = 0; k0 < 256; k0 += 32) {
            bf16x8 bn[4];
            if (k0 + 32 < 256) {
                #pragma unroll
                for (int nt = 0; nt < 4; ++nt)
                    bn[nt] = *(const bf16x8*)(pB[nt] + k0 + 32);
            }
            const int kc = k0 + lh * 8;
            const bf16x8 a0f = *(const bf16x8*)&hl[lr][kc];
            const bf16x8 a1f = *(const bf16x8*)&hl[16 + lr][kc];
            #pragma unroll
            for (int nt = 0; nt < 4; ++nt) {
                acc2[0][nt] = MFMA16(a0f, bc[nt], acc2[0][nt]);
                acc2[1][nt] = MFMA16(a1f, bc[nt], acc2[1][nt]);
            }
            #pragma unroll
            for (int nt = 0; nt < 4; ++nt) bc[nt] = bn[nt];
        }
        __syncthreads();
        #pragma unroll
        for (int nt = 0; nt < 4; ++nt) {
            const int n = nbase + nt * 16 + lr;
            const float bv = zb2[n];
            #pragma unroll
            for (int mt = 0; mt < 2; ++mt)
                #pragma unroll
                for (int v = 0; v < 4; ++v) {
                    float xv = acc2[mt][nt][v] + bv;
                    xv = xv >= 0.f ? xv : 0.01f * xv;
                    hl[mt * 16 + lh * 4 + v][n] = __float2bfloat16(xv);
                }
        }
    }
    __syncthreads();

    // ---- Layer 3: K=256 -> qr (fp32, bias, no act) ----
    {
        f32x4 acc3[2][4] = {};
        const __hip_bfloat16* pB[4];
        #pragma unroll
        for (int nt = 0; nt < 4; ++nt)
            pB[nt] = zT3 + (size_t)(nbase + nt * 16 + lr) * 256 + lh * 8;
        bf16x8 bc[4];
        #pragma unroll
        for (int nt = 0; nt < 4; ++nt) bc[nt] = *(const bf16x8*)(pB[nt]);
        #pragma unroll
        for (int k0 = 0; k0 < 256; k0 += 32) {
            bf16x8 bn[4];
            if (k0 + 32 < 256) {
                #pragma unroll
                for (int nt = 0; nt < 4; ++nt)
                    bn[nt] = *(const bf16x8*)(pB[nt] + k0 + 32);
            }
            const int kc = k0 + lh * 8;
            const bf16x8 a0f = *(const bf16x8*)&hl[lr][kc];
            const bf16x8 a1f = *(const bf16x8*)&hl[16 + lr][kc];
            #pragma unroll
            for (int nt = 0; nt < 4; ++nt) {
                acc3[0][nt] = MFMA16(a0f, bc[nt], acc3[0][nt]);
                acc3[1][nt] = MFMA16(a1f, bc[nt], acc3[1][nt]);
            }
            #pragma unroll
            for (int nt = 0; nt < 4; ++nt) bc[nt] = bn[nt];
        }
        #pragma unroll
        for (int nt = 0; nt < 4; ++nt) {
            const int n = nbase + nt * 16 + lr;
            const float bv = zb3[n];
            #pragma unroll
            for (int mt = 0; mt < 2; ++mt)
                #pragma unroll
                for (int v = 0; v < 4; ++v)
                    qr[(size_t)(a0 + mt * 16 + lh * 4 + v) * 256 + n] = acc3[mt][nt][v] + bv;
        }
    }
    #undef LOADC
    #undef WRITEC
}

// ---------------------------------------------------------------------------
// pr = ph[24576][2048] @ vT  (fp32 out, no bias/act).
// ---------------------------------------------------------------------------
__global__ __launch_bounds__(256, 3) void pr_kernel(
    const __hip_bfloat16* __restrict__ x, const __hip_bfloat16* __restrict__ vT,
    float* __restrict__ out)
{
    __shared__ __align__(16) __hip_bfloat16 xl[2][32][264];  // 33,792 B

    const int tid = threadIdx.x;
    const int a0  = blockIdx.x * 32;
    const int wv  = tid >> 6;
    const int l   = tid & 63;
    const int lr  = l & 15;
    const int lh  = l >> 4;
    const int nbase = wv * 64;

    int4 st[4];
    #define LOADC(c)                                                          \
        { _Pragma("unroll")                                                   \
          for (int it = 0; it < 4; ++it) {                                    \
              const int g = tid + it * 256;                                   \
              const int m = g >> 5, c8 = (g & 31) * 8;                        \
              st[it] = *(const int4*)&x[(size_t)(a0 + m) * 2048 + (c) * 256 + c8]; } }
    #define WRITEC(buf)                                                       \
        { _Pragma("unroll")                                                   \
          for (int it = 0; it < 4; ++it) {                                    \
              const int g = tid + it * 256;                                   \
              const int m = g >> 5, c8 = (g & 31) * 8;                        \
              *(int4*)&xl[buf][m][c8] = st[it]; } }

    f32x4 acc[2][4] = {};
    const __hip_bfloat16* pB[4];
    #pragma unroll
    for (int nt = 0; nt < 4; ++nt)
        pB[nt] = vT + (size_t)(nbase + nt * 16 + lr) * 2048 + lh * 8;

    LOADC(0); WRITEC(0); __syncthreads();
    for (int c = 0; c < 8; ++c) {
        if (c < 7) LOADC(c + 1);
        const __hip_bfloat16 (* const cur)[264] = xl[c & 1];
        bf16x8 bc[4];
        #pragma unroll
        for (int nt = 0; nt < 4; ++nt) bc[nt] = *(const bf16x8*)(pB[nt] + c * 256);
        #pragma unroll
        for (int k0 = 0; k0 < 256; k0 += 32) {
            bf16x8 bn[4];
            if (k0 + 32 < 256) {
                #pragma unroll
                for (int nt = 0; nt < 4; ++nt)
                    bn[nt] = *(const bf16x8*)(pB[nt] + c * 256 + k0 + 32);
            }
            const int kc = k0 + lh * 8;
            const bf16x8 a0f = *(const bf16x8*)&cur[lr][kc];
            const bf16x8 a1f = *(const bf16x8*)&cur[16 + lr][kc];
            #pragma unroll
            for (int nt = 0; nt < 4; ++nt) {
                acc[0][nt] = MFMA16(a0f, bc[nt], acc[0][nt]);
                acc[1][nt] = MFMA16(a1f, bc[nt], acc[1][nt]);
            }
            #pragma unroll
            for (int nt = 0; nt < 4; ++nt) bc[nt] = bn[nt];
        }
        if (c < 7) WRITEC((c + 1) & 1);
        __syncthreads();
    }
    #pragma unroll
    for (int nt = 0; nt < 4; ++nt) {
        const int n = nbase + nt * 16 + lr;
        #pragma unroll
        for (int mt = 0; mt < 2; ++mt)
            #pragma unroll
            for (int v = 0; v < 4; ++v)
                out[(size_t)(a0 + mt * 16 + lh * 4 + v) * 256 + n] = acc[mt][nt][v];
    }
    #undef LOADC
    #undef WRITEC
}

// ---------------------------------------------------------------------------
extern "C" void kernel_launch(void* const* d_in, const int* in_sizes, int n_in,
                              void* d_out, int out_size, void* d_ws, size_t ws_size,
                              hipStream_t stream)
{
    const float* q    = (const float*)d_in[0];
    const float* p    = (const float*)d_in[1];
    const float* amsk = (const float*)d_in[2];
    const float* sw1  = (const float*)d_in[3];
    const float* sb1  = (const float*)d_in[4];
    const float* sw2  = (const float*)d_in[5];
    const float* sb2  = (const float*)d_in[6];
    const float* sw3  = (const float*)d_in[7];
    const float* sb3  = (const float*)d_in[8];
    const float* zw1  = (const float*)d_in[9];
    const float* zb1  = (const float*)d_in[10];
    const float* zw2  = (const float*)d_in[11];
    const float* zb2  = (const float*)d_in[12];
    const float* zw3  = (const float*)d_in[13];
    const float* zb3  = (const float*)d_in[14];
    const float* zvw  = (const float*)d_in[15];

    // workspace carve-up
    char* ws = (char*)d_ws;
    size_t off = 0;
    __hip_bfloat16* qh   = (__hip_bfloat16*)(ws + off);  off += (size_t)R_TOT * 2048 * 2;      // 33,554,432
    __hip_bfloat16* ph   = (__hip_bfloat16*)(ws + off);  off += (size_t)R_TOT * 3 * 2048 * 2;  // 100,663,296
    __hip_bfloat16* wT1  = (__hip_bfloat16*)(ws + off);  off += 256 * 512 * 2;
    __hip_bfloat16* wT2  = (__hip_bfloat16*)(ws + off);  off += 256 * 256 * 2;
    __hip_bfloat16* wT3  = (__hip_bfloat16*)(ws + off);  off += 16 * 256 * 2;
    __hip_bfloat16* zT1  = (__hip_bfloat16*)(ws + off);  off += 256 * 2048 * 2;
    __hip_bfloat16* zT2  = (__hip_bfloat16*)(ws + off);  off += 256 * 256 * 2;
    __hip_bfloat16* zT3  = (__hip_bfloat16*)(ws + off);  off += 256 * 256 * 2;
    __hip_bfloat16* vT   = (__hip_bfloat16*)(ws + off);  off += 256 * 2048 * 2;

    float* qr = (float*)d_out;
    float* pr = (float*)d_out + QR_ELEMS;

    // 0) weight transpose + bf16 cast
    wtrans_kernel<<<dim3(16, 8), 256, 0, stream>>>(sw1, wT1, 512, 256);
    wtrans_kernel<<<dim3(8, 8),  256, 0, stream>>>(sw2, wT2, 256, 256);
    wtrans_kernel<<<dim3(8, 1),  256, 0, stream>>>(sw3, wT3, 256, 16);
    wtrans_kernel<<<dim3(64, 8), 256, 0, stream>>>(zw1, zT1, 2048, 256);
    wtrans_kernel<<<dim3(8, 8),  256, 0, stream>>>(zw2, zT2, 256, 256);
    wtrans_kernel<<<dim3(8, 8),  256, 0, stream>>>(zw3, zT3, 256, 256);
    wtrans_kernel<<<dim3(64, 8), 256, 0, stream>>>(zvw, vT, 2048, 256);

    // 1) fused sam MLP + softmax + pooling  (4 residues / block, M=64)
    sampool_kernel<<<R_TOT / 4, 256, 0, stream>>>(q, p, amsk, wT1, sb1, wT2, sb2, wT3, sb3, qh, ph);
    // 2) fused zdm MLP -> qr
    zdm_kernel<<<R_TOT / 32, 256, 0, stream>>>(qh, zT1, zb1, zT2, zb2, zT3, zb3, qr);
    // 3) pr = ph @ zdm_vec_w
    pr_kernel<<<(R_TOT * 3) / 32, 256, 0, stream>>>(ph, vT, pr);

    (void)in_sizes; (void)n_in; (void)out_size; (void)ws_size;
}